// Round 7
// baseline (1740.828 us; speedup 1.0000x reference)
//
#include <hip/hip_runtime.h>

#define T_LEN 512
#define B_SZ  64
#define I_SZ  512
#define H_SZ  512

using half8   = __attribute__((ext_vector_type(8))) _Float16;
using half4   = __attribute__((ext_vector_type(4))) _Float16;
using float4v = __attribute__((ext_vector_type(4))) float;

__device__ __forceinline__ float fast_tanh(float x) {
    // 1 - 2/(e^{2x}+1): monotone, saturates to +/-1, no NaN (inf -> 1, 0 -> -1)
    float e = __expf(2.0f * x);
    return 1.0f - 2.0f * __builtin_amdgcn_rcpf(e + 1.0f);
}

// ---------------------------------------------------------------------------
// Kernel 1: input projection GEMM. R7: 256x256 tile (was 128x128) — halves
// staged L2/L3 traffic (2048x512KB = 1GB -> 512x1MB = 512MB), 64 KB LDS
// allows 2 blocks/CU. Same granule-XOR LDS layout and frag conventions as
// the proven R6 version; 512 thr = 8 waves in a 2m x 4n grid (128x64 each).
// ---------------------------------------------------------------------------
__global__ __launch_bounds__(512) void xproj_kernel(
    const float* __restrict__ x,
    const float* __restrict__ Wf, const float* __restrict__ bf,
    const float* __restrict__ Wb, const float* __restrict__ bb,
    _Float16* __restrict__ xp)
{
    __shared__ _Float16 Ash[16384];  // 16 panels x 1024 f16 (256 m-rows x 64 k)
    __shared__ _Float16 Bsh[16384];  // 16 panels x 1024 f16 (256 n-rows x 64 k)

    const int bid = blockIdx.x;                    // 0..511
    const int swz = (bid & 7) * 64 + (bid >> 3);   // bijective XCD swizzle
    const int dir = swz & 1;
    const int nb  = (swz >> 1) & 1;
    const int mb  = swz >> 2;                      // 0..127
    const int m0  = mb * 256;
    const int n0  = nb * 256;

    const float* __restrict__ W    = dir ? Wb : Wf;
    const float* __restrict__ bias = dir ? bb : bf;

    const int tid  = threadIdx.x;
    const int wv   = tid >> 6;
    const int lane = tid & 63;
    const int lm   = lane & 15;
    const int lq   = lane >> 4;
    const int wm   = wv >> 2;          // m-half 0..1   (128 rows)
    const int wn   = wv & 3;           // n-quarter 0..3 (64 cols)

    // staging: thread owns granules q = r*512 + tid (r=0..3) of A and of B.
    // granule q: row = q>>3 (0..255), khi = q&7 (8 k-elems).
    int rowA[4], ldsA[4];
    #pragma unroll
    for (int r = 0; r < 4; r++) {
        const int q   = r*512 + tid;
        const int row = q >> 3;
        const int khi = q & 7;
        rowA[r] = row;
        ldsA[r] = (row >> 4)*1024 + (khi*16 + ((row & 15) ^ khi))*8;
    }

    float4v acc[8][4];
    #pragma unroll
    for (int mt = 0; mt < 8; mt++)
        #pragma unroll
        for (int nt = 0; nt < 4; nt++)
            acc[mt][nt] = (float4v){0,0,0,0};

    for (int k0 = 0; k0 < I_SZ; k0 += 64) {
        float4v st[16];
        #pragma unroll
        for (int r = 0; r < 4; r++) {
            const int q   = r*512 + tid;
            const int khi = q & 7;
            const float* ga = x + (size_t)(m0 + rowA[r])*I_SZ + k0 + khi*8;
            const float* gb = W + (size_t)(n0 + rowA[r])*I_SZ + k0 + khi*8;
            st[r*2]     = *(const float4v*)ga;
            st[r*2 + 1] = *(const float4v*)(ga + 4);
            st[8 + r*2]     = *(const float4v*)gb;
            st[8 + r*2 + 1] = *(const float4v*)(gb + 4);
        }
        __syncthreads();   // all waves done reading previous iter's frags
        #pragma unroll
        for (int r = 0; r < 4; r++) {
            half8 va, vb;
            #pragma unroll
            for (int e = 0; e < 4; e++) {
                va[e]   = (_Float16)st[r*2][e];
                va[e+4] = (_Float16)st[r*2+1][e];
                vb[e]   = (_Float16)st[8+r*2][e];
                vb[e+4] = (_Float16)st[8+r*2+1][e];
            }
            *(half8*)&Ash[ldsA[r]] = va;
            *(half8*)&Bsh[ldsA[r]] = vb;
        }
        __syncthreads();   // staging visible

        #pragma unroll
        for (int ks = 0; ks < 2; ks++) {
            const int khi = ks*4 + lq;
            const int go  = (khi*16 + (lm ^ khi))*8;
            half8 bfr[4];
            #pragma unroll
            for (int nt = 0; nt < 4; nt++)
                bfr[nt] = *(const half8*)&Bsh[(wn*4 + nt)*1024 + go];
            #pragma unroll
            for (int mt = 0; mt < 8; mt++) {
                half8 afr = *(const half8*)&Ash[(wm*8 + mt)*1024 + go];
                #pragma unroll
                for (int nt = 0; nt < 4; nt++)
                    acc[mt][nt] = __builtin_amdgcn_mfma_f32_16x16x32_f16(
                        afr, bfr[nt], acc[mt][nt], 0, 0, 0);
            }
        }
    }

    // epilogue: bias add, store f16 to xp[dir][t][b][n]  (m = b*T + t)
    #pragma unroll
    for (int nt = 0; nt < 4; nt++) {
        const int n  = n0 + wn*64 + nt*16 + lm;
        const float bv = bias[n];
        #pragma unroll
        for (int mt = 0; mt < 8; mt++) {
            #pragma unroll
            for (int j = 0; j < 4; j++) {
                const int m = m0 + wm*128 + mt*16 + lq*4 + j;
                const int b = m >> 9;          // T = 512
                const int t = m & 511;
                xp[(((size_t)dir*T_LEN + t)*B_SZ + b)*H_SZ + n] =
                    (_Float16)(acc[mt][nt][j] + bv);
            }
        }
    }
}

// ---------------------------------------------------------------------------
// Kernel 2: recurrence. R7 changes vs the passing R6/R5 kernel:
//  (1) hl double-buffered [2][8192] (32 KB; total LDS = 160 KiB exactly)
//      -> ONE lgkm-drain + barrier per step instead of two. Safety: a wave's
//      reads of buf[p] are consumed (hence retired) before its own pre-
//      barrier drain, so by the time ANY wave passes the step-s barrier,
//      every wave's buf[p] reads are done; step s+1 writes go to buf[p^1]...
//      which is only re-read after the NEXT barrier — induction holds.
//  (2) publish-early epilogue: per batch row j, tanh -> pack -> ds_write
//      (publish) -> y-store, so LDS publish issues during the tanh phase
//      and the pre-barrier drain covers almost nothing.
// Everything else (wave layout, weight split 48 reg-frags + 16 LDS-frags,
// granule-XOR hl layout, frag conventions) identical to R5/R6.
// ---------------------------------------------------------------------------
__global__ __launch_bounds__(512, 2) void rnn_kernel(
    const _Float16* __restrict__ xp,     // [2][T][B][H] f16
    const float* __restrict__ Whf, const float* __restrict__ Whb,
    const float* __restrict__ h0f, const float* __restrict__ h0b,
    float* __restrict__ out)             // y[B][T][2H] ++ hTf ++ hTb
{
    const int blk  = blockIdx.x;         // 0..7
    const int dir  = blk >> 2;
    const int b0   = (blk & 3) * 16;
    const int tid  = threadIdx.x;
    const int wv   = tid >> 6;           // 0..7
    const int lane = tid & 63;
    const int lq   = lane >> 4;
    const int lm   = lane & 15;

    const float* __restrict__ Wh = dir ? Whb : Whf;
    const float* __restrict__ h0 = dir ? h0b : h0f;

    __shared__ _Float16 hl[2][8192];          // 32 KB: h ping-pong, swizzled granules
    __shared__ _Float16 wl[8][16][64][8];     // 128 KB: per-wave LDS weight frags

    // ---- one-time: Wh rows n = wv*64 + lm*4 + nt -> f16 B-fragments ----
    half8 bw[4][12];
    {
        const float* wr0 = Wh + ((size_t)(wv*64 + lm*4)) * H_SZ + lq*8;
        #pragma unroll
        for (int nt = 0; nt < 4; nt++) {
            const float* wr = wr0 + (size_t)nt * H_SZ;
            #pragma unroll
            for (int kt = 0; kt < 16; kt++) {
                float4v lo = *(const float4v*)(wr + kt*32);
                float4v hi = *(const float4v*)(wr + kt*32 + 4);
                half8 v;
                #pragma unroll
                for (int e = 0; e < 4; e++) { v[e] = (_Float16)lo[e]; v[e+4] = (_Float16)hi[e]; }
                if (kt < 12) bw[nt][kt] = v;
                else *(half8*)&wl[wv][nt*4 + (kt - 12)][lane][0] = v;
            }
        }
    }

    // ---- stage h0 into hl[0] (granule (khi,b) <- h0[b][khi*8..+8)) ----
    #pragma unroll
    for (int r = 0; r < 2; r++) {
        const int gi  = r*512 + tid;          // 0..1023 granules
        const int khi = gi >> 4;
        const int b   = gi & 15;
        const float* p = h0 + (size_t)(b0 + b)*H_SZ + khi*8;
        half8 v;
        #pragma unroll
        for (int e = 0; e < 8; e++) v[e] = (_Float16)p[e];
        *(half8*)&hl[0][(khi*16 + (b ^ (khi & 15))) * 8] = v;
    }
    __syncthreads();

    const _Float16* wlp = &wl[wv][0][lane][0];     // + frag*512 f16 (imm-foldable)

    const int ts = dir ? -1 : 1;
    const int t0 = dir ? (T_LEN - 1) : 0;
    const _Float16* xpt = xp + (((size_t)dir*T_LEN + t0)*B_SZ + (b0 + lq*4))*H_SZ
                             + wv*64 + lm*4;
    const ptrdiff_t xstep = (ptrdiff_t)ts * (B_SZ * H_SZ);
    float* yb = out + ((size_t)(b0 + lq*4)*T_LEN + t0)*1024 + dir*512 + wv*64 + lm*4;
    const ptrdiff_t ystep = (ptrdiff_t)ts * 1024;

    const int khiw = wv*8 + (lm >> 1);    // granule row of this thread's outputs
    const int gofs = (lm & 1) * 4;        // f16 offset within the granule

    half4 xq[4];
    #pragma unroll
    for (int j = 0; j < 4; j++) xq[j] = *(const half4*)(xpt + j*H_SZ);

    #pragma unroll 1
    for (int s = 0; s < T_LEN; s++) {
        const _Float16* hr = hl[s & 1];           // read buffer
        _Float16*       hw = hl[(s & 1) ^ 1];     // write buffer

        // acc init = xp (consumes xq), then prefetch next step's xp
        float4v acc[4];
        #pragma unroll
        for (int nt = 0; nt < 4; nt++)
            #pragma unroll
            for (int j = 0; j < 4; j++)
                acc[nt][j] = (float)xq[j][nt];

        if (s + 1 < T_LEN) {
            xpt += xstep;
            #pragma unroll
            for (int j = 0; j < 4; j++) xq[j] = *(const half4*)(xpt + j*H_SZ);
        }

        // kt 0..11: B from registers, A streamed in 4-chunks
        #pragma unroll
        for (int g = 0; g < 3; g++) {
            half8 af[4];
            #pragma unroll
            for (int i = 0; i < 4; i++) {
                const int c = (g*4 + i)*4 + lq;
                af[i] = *(const half8*)&hr[(c*16 + (lm ^ (c & 15))) * 8];
            }
            #pragma unroll
            for (int i = 0; i < 4; i++)
                #pragma unroll
                for (int nt = 0; nt < 4; nt++)
                    acc[nt] = __builtin_amdgcn_mfma_f32_16x16x32_f16(af[i], bw[nt][g*4 + i], acc[nt], 0, 0, 0);
        }
        // kt 12..15: B from LDS
        {
            half8 af[4];
            #pragma unroll
            for (int i = 0; i < 4; i++) {
                const int c = (12 + i)*4 + lq;
                af[i] = *(const half8*)&hr[(c*16 + (lm ^ (c & 15))) * 8];
            }
            #pragma unroll
            for (int i = 0; i < 4; i++)
                #pragma unroll
                for (int nt = 0; nt < 4; nt++) {
                    half8 w = *(const half8*)(wlp + (nt*4 + i)*512);
                    acc[nt] = __builtin_amdgcn_mfma_f32_16x16x32_f16(af[i], w, acc[nt], 0, 0, 0);
                }
        }

        // epilogue per batch row j: tanh -> pack -> PUBLISH (LDS) -> y store
        #pragma unroll
        for (int j = 0; j < 4; j++) {
            float4v v;
            #pragma unroll
            for (int nt = 0; nt < 4; nt++) v[nt] = fast_tanh(acc[nt][j]);
            half4 pk;
            #pragma unroll
            for (int nt = 0; nt < 4; nt++) pk[nt] = (_Float16)v[nt];
            *(half4*)&hw[(khiw*16 + ((lq*4 + j) ^ (khiw & 15))) * 8 + gofs] = pk;
            __builtin_nontemporal_store(v, (float4v*)(yb + (size_t)j*(T_LEN*1024)));
            if (s == T_LEN - 1) {
                float* hp = out + 33554432 + (size_t)dir*32768
                          + (size_t)(b0 + lq*4 + j)*H_SZ + wv*64 + lm*4;
                __builtin_nontemporal_store(v, (float4v*)hp);
            }
        }
        yb += ystep;

        // single barrier per step: publish writes drained, then rendezvous
        asm volatile("s_waitcnt lgkmcnt(0)" ::: "memory");
        __builtin_amdgcn_s_barrier();
        __builtin_amdgcn_sched_barrier(0);
    }
}

// ---------------------------------------------------------------------------
// ws layout (bytes):
//   [0, 67108864)  xp : 2*512*64*512 f16
// ---------------------------------------------------------------------------
extern "C" void kernel_launch(void* const* d_in, const int* in_sizes, int n_in,
                              void* d_out, int out_size, void* d_ws, size_t ws_size,
                              hipStream_t stream) {
    const float* x   = (const float*)d_in[0];
    const float* h0f = (const float*)d_in[1];
    const float* h0b = (const float*)d_in[2];
    const float* Wxf = (const float*)d_in[3];
    const float* bxf = (const float*)d_in[4];
    const float* Whf = (const float*)d_in[5];
    const float* Wxb = (const float*)d_in[6];
    const float* bxb = (const float*)d_in[7];
    const float* Whb = (const float*)d_in[8];
    float* out = (float*)d_out;

    _Float16* xpb = (_Float16*)d_ws;

    hipLaunchKernelGGL(xproj_kernel, dim3(512), dim3(512), 0, stream,
                       x, Wxf, bxf, Wxb, bxb, xpb);
    hipLaunchKernelGGL(rnn_kernel, dim3(8), dim3(512), 0, stream,
                       xpb, Whf, Whb, h0f, h0b, out);
}

// Round 8
// 1453.925 us; speedup vs baseline: 1.1973x; 1.1973x over previous
//
#include <hip/hip_runtime.h>

#define T_LEN 512
#define B_SZ  64
#define I_SZ  512
#define H_SZ  512

using half8   = __attribute__((ext_vector_type(8))) _Float16;
using half4   = __attribute__((ext_vector_type(4))) _Float16;
using float4v = __attribute__((ext_vector_type(4))) float;

__device__ __forceinline__ float fast_tanh(float x) {
    // 1 - 2/(e^{2x}+1): monotone, saturates to +/-1, no NaN (inf -> 1, 0 -> -1)
    float e = __expf(2.0f * x);
    return 1.0f - 2.0f * __builtin_amdgcn_rcpf(e + 1.0f);
}

// ---------------------------------------------------------------------------
// FUSED kernel. Blocks 0..7: the R6 rnn (verbatim — R7's single-barrier
// variant regressed 4% and is reverted). Blocks 8..519: the R7-proven 256^2
// GEMM re-tiled so each block produces xp for a 4-timestep slab x all 64
// batches x 256 n-dims (tile row r -> (b = r>>2, t = ts4*4 + (r&3)); pure
// row relabeling, MFMA/staging math identical to the passing R7 xproj).
//
// Producer/consumer protocol (same class as the R0 baseline's slab+flags,
// but 2 rendezvous per 4 steps instead of 4 per step):
//   producer: stores -> s_waitcnt vmcnt(0) -> __syncthreads ->
//             tid0: atomicAdd(cnt[dir*128+ts4], 1, RELEASE, AGENT)
//             (release at agent scope writes back L2 so xp reaches L3
//              before the flag does)
//   consumer: before the xq prefetch crosses into slab S:
//             tid0 spins on acquire-AGENT load of cnt[dir*128+S] < 2
//             (acquire invalidates local L2 -> stale lines from the
//              previous graph replay are dropped), then __syncthreads.
// Production order: fwd slabs ascending, bwd descending (ord = xb>>2),
// so each direction's first slab is produced by the earliest blocks.
// Correctness does not depend on dispatch order — only overlap quality.
// ---------------------------------------------------------------------------
__global__ __launch_bounds__(512, 2) void fused_kernel(
    const float* __restrict__ x,
    const float* __restrict__ Wxf, const float* __restrict__ bxf,
    const float* __restrict__ Whf,
    const float* __restrict__ Wxb, const float* __restrict__ bxb,
    const float* __restrict__ Whb,
    const float* __restrict__ h0f, const float* __restrict__ h0b,
    _Float16* __restrict__ xp,           // [2][T][B][H] f16 (workspace)
    float* __restrict__ out,             // y[B][T][2H] ++ hTf ++ hTb
    unsigned int* __restrict__ cnt)      // [2][128] slab counters (zeroed)
{
    __shared__ _Float16 smem[73728];     // 144 KB, union of both paths

    const int tid  = threadIdx.x;
    const int wv   = tid >> 6;
    const int lane = tid & 63;
    const int lm   = lane & 15;
    const int lq   = lane >> 4;

    if (blockIdx.x >= 8) {
        // ================= xproj producer =================
        const int xb  = blockIdx.x - 8;        // 0..511
        const int ord = xb >> 2;               // 0..127 production order
        const int sub = xb & 3;
        const int dir = sub & 1;
        const int nb  = sub >> 1;
        const int ts4 = dir ? (127 - ord) : ord;   // 4-t slab this block makes
        const int n0  = nb * 256;

        const float* __restrict__ W    = dir ? Wxb : Wxf;
        const float* __restrict__ bias = dir ? bxb : bxf;

        _Float16* Ash = smem;                  // 16384 f16 (32 KB)
        _Float16* Bsh = smem + 16384;          // 16384 f16 (32 KB)

        const int wm = wv >> 2;                // 0..1 (128 rows)
        const int wn = wv & 3;                 // 0..3 (64 cols)

        float4v acc[8][4];
        #pragma unroll
        for (int mt = 0; mt < 8; mt++)
            #pragma unroll
            for (int nt = 0; nt < 4; nt++)
                acc[mt][nt] = (float4v){0,0,0,0};

        for (int k0 = 0; k0 < I_SZ; k0 += 64) {
            float4v st[16];
            #pragma unroll
            for (int rr = 0; rr < 4; rr++) {
                const int q   = rr*512 + tid;
                const int row = q >> 3;
                const int khi = q & 7;
                const int bb  = row >> 2;
                const int tt  = ts4*4 + (row & 3);
                const float* ga = x + ((size_t)bb*T_LEN + tt)*I_SZ + k0 + khi*8;
                const float* gb = W + (size_t)(n0 + row)*I_SZ + k0 + khi*8;
                st[rr*2]       = *(const float4v*)ga;
                st[rr*2 + 1]   = *(const float4v*)(ga + 4);
                st[8 + rr*2]   = *(const float4v*)gb;
                st[8 + rr*2+1] = *(const float4v*)(gb + 4);
            }
            __syncthreads();   // all waves done reading previous iter's frags
            #pragma unroll
            for (int rr = 0; rr < 4; rr++) {
                const int q   = rr*512 + tid;
                const int row = q >> 3;
                const int khi = q & 7;
                const int lo_ = (row >> 4)*1024 + (khi*16 + ((row & 15) ^ khi))*8;
                half8 va, vb;
                #pragma unroll
                for (int e = 0; e < 4; e++) {
                    va[e]   = (_Float16)st[rr*2][e];
                    va[e+4] = (_Float16)st[rr*2+1][e];
                    vb[e]   = (_Float16)st[8+rr*2][e];
                    vb[e+4] = (_Float16)st[8+rr*2+1][e];
                }
                *(half8*)&Ash[lo_] = va;
                *(half8*)&Bsh[lo_] = vb;
            }
            __syncthreads();   // staging visible

            #pragma unroll
            for (int ks = 0; ks < 2; ks++) {
                const int khi = ks*4 + lq;
                const int go  = (khi*16 + (lm ^ khi))*8;
                half8 bfr[4];
                #pragma unroll
                for (int nt = 0; nt < 4; nt++)
                    bfr[nt] = *(const half8*)&Bsh[(wn*4 + nt)*1024 + go];
                #pragma unroll
                for (int mt = 0; mt < 8; mt++) {
                    half8 afr = *(const half8*)&Ash[(wm*8 + mt)*1024 + go];
                    #pragma unroll
                    for (int nt = 0; nt < 4; nt++)
                        acc[mt][nt] = __builtin_amdgcn_mfma_f32_16x16x32_f16(
                            afr, bfr[nt], acc[mt][nt], 0, 0, 0);
                }
            }
        }

        // epilogue: bias add, f16 store to xp[dir][t][b][n]
        #pragma unroll
        for (int nt = 0; nt < 4; nt++) {
            const int n  = n0 + wn*64 + nt*16 + lm;
            const float bv = bias[n];
            #pragma unroll
            for (int mt = 0; mt < 8; mt++) {
                #pragma unroll
                for (int j = 0; j < 4; j++) {
                    const int row = wm*128 + mt*16 + lq*4 + j;
                    const int bb  = row >> 2;
                    const int tt  = ts4*4 + (row & 3);
                    xp[(((size_t)dir*T_LEN + tt)*B_SZ + bb)*H_SZ + n] =
                        (_Float16)(acc[mt][nt][j] + bv);
                }
            }
        }

        // publish: drain stores to L2, rendezvous, release flag (wb L2 -> L3)
        asm volatile("s_waitcnt vmcnt(0)" ::: "memory");
        __syncthreads();
        if (tid == 0)
            __hip_atomic_fetch_add(&cnt[dir*128 + ts4], 1u,
                                   __ATOMIC_RELEASE, __HIP_MEMORY_SCOPE_AGENT);
        return;
    }

    // ================= rnn consumer (verbatim R6 + slab polls) =================
    const int blk = blockIdx.x;          // 0..7
    const int dir = blk >> 2;
    const int b0  = (blk & 3) * 16;

    const float* __restrict__ Wh = dir ? Whb : Whf;
    const float* __restrict__ h0 = dir ? h0b : h0f;

    _Float16* hl  = smem;                // 8192 f16 (16 KB), swizzled granules
    _Float16* wlb = smem + 8192;         // 65536 f16 (128 KB), LDS weight frags

    // ---- one-time: Wh rows n = wv*64 + lm*4 + nt -> f16 B-fragments ----
    half8 bw[4][12];
    {
        const float* wr0 = Wh + ((size_t)(wv*64 + lm*4)) * H_SZ + lq*8;
        #pragma unroll
        for (int nt = 0; nt < 4; nt++) {
            const float* wr = wr0 + (size_t)nt * H_SZ;
            #pragma unroll
            for (int kt = 0; kt < 16; kt++) {
                float4v lo = *(const float4v*)(wr + kt*32);
                float4v hi = *(const float4v*)(wr + kt*32 + 4);
                half8 v;
                #pragma unroll
                for (int e = 0; e < 4; e++) { v[e] = (_Float16)lo[e]; v[e+4] = (_Float16)hi[e]; }
                if (kt < 12) bw[nt][kt] = v;
                else *(half8*)&wlb[wv*8192 + (nt*4 + (kt - 12))*512 + lane*8] = v;
            }
        }
    }

    // ---- stage h0 into hl (granule (khi,b) <- h0[b][khi*8..+8)) ----
    #pragma unroll
    for (int r = 0; r < 2; r++) {
        const int gi  = r*512 + tid;          // 0..1023 granules
        const int khi = gi >> 4;
        const int b   = gi & 15;
        const float* p = h0 + (size_t)(b0 + b)*H_SZ + khi*8;
        half8 v;
        #pragma unroll
        for (int e = 0; e < 8; e++) v[e] = (_Float16)p[e];
        *(half8*)&hl[(khi*16 + (b ^ (khi & 15))) * 8] = v;
    }
    __syncthreads();

    const _Float16* wlp = wlb + wv*8192 + lane*8;   // + frag*512 f16

    const int ts = dir ? -1 : 1;
    const int t0 = dir ? (T_LEN - 1) : 0;
    const _Float16* xpt = xp + (((size_t)dir*T_LEN + t0)*B_SZ + (b0 + lq*4))*H_SZ
                             + wv*64 + lm*4;
    const ptrdiff_t xstep = (ptrdiff_t)ts * (B_SZ * H_SZ);
    float* yb = out + ((size_t)(b0 + lq*4)*T_LEN + t0)*1024 + dir*512 + wv*64 + lm*4;
    const ptrdiff_t ystep = (ptrdiff_t)ts * 1024;

    const int khiw = wv*8 + (lm >> 1);    // granule row of this thread's outputs
    const int gofs = (lm & 1) * 4;        // f16 offset within the granule

    // wait for this direction's first 4-t slab, then prefetch
    {
        const unsigned int* f = cnt + dir*128 + (t0 >> 2);
        if (tid == 0)
            while (__hip_atomic_load(f, __ATOMIC_ACQUIRE,
                                     __HIP_MEMORY_SCOPE_AGENT) < 2u) {}
        __syncthreads();
    }

    half4 xq[4];
    #pragma unroll
    for (int j = 0; j < 4; j++) xq[j] = *(const half4*)(xpt + j*H_SZ);

    #pragma unroll 1
    for (int s = 0; s < T_LEN; s++) {
        // acc init = xp (consumes xq), then prefetch next step's xp
        float4v acc[4];
        #pragma unroll
        for (int nt = 0; nt < 4; nt++)
            #pragma unroll
            for (int j = 0; j < 4; j++)
                acc[nt][j] = (float)xq[j][nt];

        if (s + 1 < T_LEN) {
            // poll BEFORE the prefetch crosses into a new 4-t slab
            const int tn = dir ? (510 - s) : (s + 1);
            if ((tn & 3) == (dir ? 3 : 0)) {
                const unsigned int* f = cnt + dir*128 + (tn >> 2);
                if (tid == 0)
                    while (__hip_atomic_load(f, __ATOMIC_ACQUIRE,
                                             __HIP_MEMORY_SCOPE_AGENT) < 2u) {}
                __syncthreads();
            }
            xpt += xstep;
            #pragma unroll
            for (int j = 0; j < 4; j++) xq[j] = *(const half4*)(xpt + j*H_SZ);
        }

        // kt 0..11: B from registers, A streamed in 4-chunks
        #pragma unroll
        for (int g = 0; g < 3; g++) {
            half8 af[4];
            #pragma unroll
            for (int i = 0; i < 4; i++) {
                const int c = (g*4 + i)*4 + lq;
                af[i] = *(const half8*)&hl[(c*16 + (lm ^ (c & 15))) * 8];
            }
            #pragma unroll
            for (int i = 0; i < 4; i++)
                #pragma unroll
                for (int nt = 0; nt < 4; nt++)
                    acc[nt] = __builtin_amdgcn_mfma_f32_16x16x32_f16(af[i], bw[nt][g*4 + i], acc[nt], 0, 0, 0);
        }
        // kt 12..15: B from LDS
        {
            half8 af[4];
            #pragma unroll
            for (int i = 0; i < 4; i++) {
                const int c = (12 + i)*4 + lq;
                af[i] = *(const half8*)&hl[(c*16 + (lm ^ (c & 15))) * 8];
            }
            #pragma unroll
            for (int i = 0; i < 4; i++)
                #pragma unroll
                for (int nt = 0; nt < 4; nt++) {
                    half8 w = *(const half8*)(wlp + (nt*4 + i)*512);
                    acc[nt] = __builtin_amdgcn_mfma_f32_16x16x32_f16(af[i], w, acc[nt], 0, 0, 0);
                }
        }

        // epilogue: tanh, one float4 y store per batch row, f16 pack
        half4 pks[4];
        #pragma unroll
        for (int j = 0; j < 4; j++) {
            float4v v;
            #pragma unroll
            for (int nt = 0; nt < 4; nt++) v[nt] = fast_tanh(acc[nt][j]);
            __builtin_nontemporal_store(v, (float4v*)(yb + (size_t)j*(T_LEN*1024)));
            if (s == T_LEN - 1) {
                float* hp = out + 33554432 + (size_t)dir*32768
                          + (size_t)(b0 + lq*4 + j)*H_SZ + wv*64 + lm*4;
                __builtin_nontemporal_store(v, (float4v*)hp);
            }
            half4 pk;
            #pragma unroll
            for (int nt = 0; nt < 4; nt++) pk[nt] = (_Float16)v[nt];
            pks[j] = pk;
        }
        yb += ystep;

        // barrier A: all waves done READING hl (lgkm only — y-stores in flight)
        asm volatile("s_waitcnt lgkmcnt(0)" ::: "memory");
        __builtin_amdgcn_s_barrier();

        // publish new h: one b64 half-granule per batch row, swizzled
        #pragma unroll
        for (int j = 0; j < 4; j++)
            *(half4*)&hl[(khiw*16 + ((lq*4 + j) ^ (khiw & 15))) * 8 + gofs] = pks[j];

        // barrier B: new h visible for next step's A-frag reads
        asm volatile("s_waitcnt lgkmcnt(0)" ::: "memory");
        __builtin_amdgcn_s_barrier();
    }
}

// ---------------------------------------------------------------------------
// ws layout (bytes):
//   [0,        67108864)  xp  : 2*512*64*512 f16
//   [67108864, 67109888)  cnt : 2*128 uint slab counters (zeroed each launch)
// ---------------------------------------------------------------------------
extern "C" void kernel_launch(void* const* d_in, const int* in_sizes, int n_in,
                              void* d_out, int out_size, void* d_ws, size_t ws_size,
                              hipStream_t stream) {
    const float* x   = (const float*)d_in[0];
    const float* h0f = (const float*)d_in[1];
    const float* h0b = (const float*)d_in[2];
    const float* Wxf = (const float*)d_in[3];
    const float* bxf = (const float*)d_in[4];
    const float* Whf = (const float*)d_in[5];
    const float* Wxb = (const float*)d_in[6];
    const float* bxb = (const float*)d_in[7];
    const float* Whb = (const float*)d_in[8];
    float* out = (float*)d_out;

    _Float16*     xpb = (_Float16*)d_ws;
    unsigned int* cnt = (unsigned int*)((char*)d_ws + 67108864);

    (void)hipMemsetAsync(cnt, 0, 2 * 128 * sizeof(unsigned int), stream);

    hipLaunchKernelGGL(fused_kernel, dim3(520), dim3(512), 0, stream,
                       x, Wxf, bxf, Whf, Wxb, bxb, Whb, h0f, h0b,
                       xpb, out, cnt);
}